// Round 7
// baseline (10821.131 us; speedup 1.0000x reference)
//
#include <hip/hip_runtime.h>
#include <hip/hip_bf16.h>

// ---------------------------------------------------------------------------
// Strict f64 squared distance matching numpy float64:
//   d = ((dx*dx + dy*dy) + dz*dz), every op individually rounded, no FMA.
// ---------------------------------------------------------------------------
__device__ __forceinline__ double dist2d(float x, float y, float z,
                                         double px, double py, double pz) {
    double dx = __dsub_rn((double)x, px);
    double dy = __dsub_rn((double)y, py);
    double dz = __dsub_rn((double)z, pz);
    double a  = __dmul_rn(dx, dx);
    double b  = __dmul_rn(dy, dy);
    double c  = __dmul_rn(dz, dz);
    return __dadd_rn(__dadd_rn(a, b), c);
}

// DPP move; lanes with invalid source keep their own value (bound_ctrl=false).
template <int CTRL>
__device__ __forceinline__ double dpp_f64_keep(double v) {
    long long b = __double_as_longlong(v);
    int lo = (int)(b & 0xFFFFFFFFLL);
    int hi = (int)(((unsigned long long)b) >> 32);
    int lo2 = __builtin_amdgcn_update_dpp(lo, lo, CTRL, 0xF, 0xF, false);
    int hi2 = __builtin_amdgcn_update_dpp(hi, hi, CTRL, 0xF, 0xF, false);
    return __longlong_as_double(((long long)(unsigned)hi2 << 32) | (unsigned)lo2);
}

__device__ __forceinline__ double wave_max_f64(double v) {
    v = fmax(v, dpp_f64_keep<0x111>(v));  // row_shr:1
    v = fmax(v, dpp_f64_keep<0x112>(v));  // row_shr:2
    v = fmax(v, dpp_f64_keep<0x114>(v));  // row_shr:4
    v = fmax(v, dpp_f64_keep<0x118>(v));  // row_shr:8
    v = fmax(v, dpp_f64_keep<0x142>(v));  // row_bcast:15
    v = fmax(v, dpp_f64_keep<0x143>(v));  // row_bcast:31
    return v;                              // lane 63 holds the max
}

__device__ __forceinline__ double readlane_f64(double v, int l) {
    long long b = __double_as_longlong(v);
    int lo = __builtin_amdgcn_readlane((int)(b & 0xFFFFFFFFLL), l);
    int hi = __builtin_amdgcn_readlane((int)(((unsigned long long)b) >> 32), l);
    return __longlong_as_double(((long long)(unsigned)hi << 32) | (unsigned)lo);
}

// 10-bit part1by2 (works for <=10-bit input); we feed 6 bits.
__device__ __forceinline__ unsigned part1by2(unsigned v) {
    v = (v * 0x00010001u) & 0xFF0000FFu;
    v = (v * 0x00000101u) & 0x0F00F00Fu;
    v = (v * 0x00000011u) & 0xC30C30C3u;
    v = (v * 0x00000005u) & 0x49249249u;
    return v;
}

// ---------------------------------------------------------------------------
// Spatial sort: one block per batch. Bitonic sort of N u32 keys
// (morton18 << 13 | pos) in LDS. Emits perm_xyz [B][N][3], perm_oi [B][N],
// and pos0 (sorted position of original point 0). The Morton hash affects
// only skip efficiency downstream, never correctness.
// ---------------------------------------------------------------------------
template <int N, int NT>
__global__ __launch_bounds__(NT) void sort_kernel(
    const float* __restrict__ pts, int stride,
    float* __restrict__ perm_xyz,
    int* __restrict__ perm_oi,
    int* __restrict__ pos0s)
{
    __shared__ unsigned arr[N];
    const int batch = blockIdx.x;
    const int tid   = threadIdx.x;
    const float* base = pts + (size_t)batch * N * stride;

    for (int p = tid; p < N; p += NT) {
        const float* r = base + (size_t)p * stride;
        // clamp to [0,63]; NaN-safe (fmaxf(NaN,0)=0)
        unsigned xi = (unsigned)fminf(fmaxf((r[0] + 4.0f) * 8.0f, 0.0f), 63.0f);
        unsigned yi = (unsigned)fminf(fmaxf((r[1] + 4.0f) * 8.0f, 0.0f), 63.0f);
        unsigned zi = (unsigned)fminf(fmaxf((r[2] + 4.0f) * 8.0f, 0.0f), 63.0f);
        unsigned code = part1by2(xi) | (part1by2(yi) << 1) | (part1by2(zi) << 2);
        arr[p] = (code << 13) | (unsigned)p;
    }
    __syncthreads();

    for (int size = 2; size <= N; size <<= 1) {
        for (int str = size >> 1; str > 0; str >>= 1) {
            for (int t = tid; t < N / 2; t += NT) {
                int i = ((t & ~(str - 1)) << 1) | (t & (str - 1));
                unsigned a = arr[i], b = arr[i | str];
                bool up = ((i & size) == 0);
                if ((a > b) == up) { arr[i] = b; arr[i | str] = a; }
            }
            __syncthreads();
        }
    }

    for (int s = tid; s < N; s += NT) {
        int p = (int)(arr[s] & 0x1FFFu);
        const float* r = base + (size_t)p * stride;
        float* w = perm_xyz + ((size_t)batch * N + s) * 3;
        w[0] = r[0]; w[1] = r[1]; w[2] = r[2];
        perm_oi[(size_t)batch * N + s] = p;
        if (p == 0) pos0s[batch] = s;
    }
}

// ---------------------------------------------------------------------------
// FPS on spatially-sorted points. One block per batch.
// Sorted position s = (wv*PPT + j)*64 + lane -> each (wave,slot) is a
// contiguous spatial bucket of 64 points, so the per-slot __any screen
// fires only when the new winner is near that bucket.
// Selection is bit-exact vs numpy float64: f64 distances (strict chain),
// argmax with first-occurrence-by-ORIGINAL-index tie-break carried through
// in-lane scan, wave ballot, and cross-wave reduce. Screened-out slots are
// provably unchanged (margin 1.000004 >> fma screen error).
// ---------------------------------------------------------------------------
template <int PPT, int NT, bool MIRROR>
__global__ __launch_bounds__(NT, 2) void fps_kernel(
    const float* __restrict__ perm_xyz,  // [B][N_IN][3]
    const int* __restrict__ perm_oi,     // [B][N_IN]
    const int* __restrict__ pos0s,       // [B]
    int npoints,
    int* __restrict__ idx_out)           // [B][npoints] (original indices)
{
    constexpr int NWAVES = NT / 64;
    constexpr int N_IN   = PPT * NT;

    const int batch = blockIdx.x;
    const int tid   = threadIdx.x;
    const int lane  = tid & 63;
    const int wv    = tid >> 6;

    const float* base   = perm_xyz + (size_t)batch * N_IN * 3;
    const int*   oibase = perm_oi + (size_t)batch * N_IN;
    int* iout = idx_out + (size_t)batch * npoints;

    __shared__ double s_m[2][NWAVES];
    __shared__ int    s_s[2][NWAVES];   // sorted pos
    __shared__ int    s_o[2][NWAVES];   // original idx
    __shared__ float  s_pts[MIRROR ? N_IN * 3 : 4];

    float  cx[PPT], cy[PPT], cz[PPT];
    int    oi[PPT];
    double md[PPT];
    float  th[PPT];

#pragma unroll
    for (int j = 0; j < PPT; ++j) {
        int s = (wv * PPT + j) * 64 + lane;
        const float* r = base + (size_t)s * 3;
        cx[j] = r[0]; cy[j] = r[1]; cz[j] = r[2];
        oi[j] = oibase[s];
        if (MIRROR) {
            s_pts[s * 3 + 0] = cx[j];
            s_pts[s * 3 + 1] = cy[j];
            s_pts[s * 3 + 2] = cz[j];
        }
    }

    // first selected point: ORIGINAL index 0, at sorted position pos0
    int pos0 = min(max(pos0s[batch], 0), N_IN - 1);
    const float* q0r = base + (size_t)pos0 * 3;
    float q0x = q0r[0], q0y = q0r[1], q0z = q0r[2];
    if (tid == 0) iout[0] = 0;

    double bv = -1.0;
    int    bs = 0x7FFFFFFF;   // sorted pos of best
    int    boi = 0x7FFFFFFF;  // orig idx of best
#pragma unroll
    for (int j = 0; j < PPT; ++j) {
        md[j] = dist2d(cx[j], cy[j], cz[j], (double)q0x, (double)q0y, (double)q0z);
        th[j] = __fmul_rn((float)md[j], 1.000004f);
        if (md[j] > bv || (md[j] == bv && oi[j] < boi)) {
            bv = md[j]; bs = (wv * PPT + j) * 64 + lane; boi = oi[j];
        }
    }

    for (int i = 1; i < npoints; ++i) {
        const int par = i & 1;

        // ---- wave-level max (value only, DPP) ----
        double wmax = readlane_f64(wave_max_f64(bv), 63);
        unsigned long long cm = __ballot(bv == wmax);
        int wl;
        if (__popcll(cm) == 1) {
            wl = __ffsll(cm) - 1;
        } else {  // exact tie: lane holding min ORIGINAL index
            int mi = 0x7FFFFFFF, ml = 0;
            unsigned long long t2 = cm;
            while (t2) {
                int l  = __ffsll(t2) - 1;
                int ci = __builtin_amdgcn_readlane(boi, l);
                if (ci < mi) { mi = ci; ml = l; }
                t2 &= t2 - 1;
            }
            wl = ml;
        }
        int ws = __builtin_amdgcn_readlane(bs, wl);
        int wo = __builtin_amdgcn_readlane(boi, wl);
        if (lane == 0) { s_m[par][wv] = wmax; s_s[par][wv] = ws; s_o[par][wv] = wo; }
        __syncthreads();

        // ---- cross-wave reduce of NWAVES partials ----
        double pm = s_m[par][lane & (NWAVES - 1)];
        int    ps = s_s[par][lane & (NWAVES - 1)];
        int    po = s_o[par][lane & (NWAVES - 1)];
        double v2 = (lane < NWAVES) ? pm : -1.0;
        v2 = fmax(v2, dpp_f64_keep<0x111>(v2));
        v2 = fmax(v2, dpp_f64_keep<0x112>(v2));
        if (NWAVES == 8) v2 = fmax(v2, dpp_f64_keep<0x114>(v2));
        double gmax = readlane_f64(v2, NWAVES - 1);
        unsigned long long c2 = __ballot((lane < NWAVES) && (pm == gmax));
        int wl2;
        if (__popcll(c2) == 1) {
            wl2 = __ffsll(c2) - 1;
        } else {
            int mi = 0x7FFFFFFF, ml = 0;
            unsigned long long t2 = c2;
            while (t2) {
                int l  = __ffsll(t2) - 1;
                int ci = __builtin_amdgcn_readlane(po, l);
                if (ci < mi) { mi = ci; ml = l; }
                t2 &= t2 - 1;
            }
            wl2 = ml;
        }
        int best_s = __builtin_amdgcn_readlane(ps, wl2);
        int best_o = __builtin_amdgcn_readlane(po, wl2);
        best_s = min(max(best_s, 0), N_IN - 1);          // replay-poison safety
        if (tid == 0) iout[i] = min(max(best_o, 0), N_IN - 1);

        // winner coords: LDS mirror broadcast or clamped global broadcast
        float qx, qy, qz;
        if (MIRROR) {
            qx = s_pts[best_s * 3 + 0];
            qy = s_pts[best_s * 3 + 1];
            qz = s_pts[best_s * 3 + 2];
        } else {
            const float* rb = base + (size_t)best_s * 3;
            qx = rb[0]; qy = rb[1]; qz = rb[2];
        }
        const double qx64 = (double)qx, qy64 = (double)qy, qz64 = (double)qz;

        // ---- per-bucket screen -> wave-uniform fire mask ----
        int fmask = 0;
#pragma unroll
        for (int j = 0; j < PPT; ++j) {
            float dx = cx[j] - qx;
            float dy = cy[j] - qy;
            float dz = cz[j] - qz;
            float d32 = fmaf(dx, dx, fmaf(dy, dy, dz * dz));
            fmask |= (__any(d32 < th[j]) ? (1 << j) : 0);
        }

        if (fmask) {
#pragma unroll
            for (int j = 0; j < PPT; ++j) {
                if (fmask & (1 << j)) {
                    double d = dist2d(cx[j], cy[j], cz[j], qx64, qy64, qz64);
                    md[j] = fmin(md[j], d);
                    th[j] = __fmul_rn((float)md[j], 1.000004f);
                }
            }
            // full rescan (md decreases may dethrone the holder)
            bv = -1.0; bs = 0x7FFFFFFF; boi = 0x7FFFFFFF;
#pragma unroll
            for (int j = 0; j < PPT; ++j) {
                if (md[j] > bv || (md[j] == bv && oi[j] < boi)) {
                    bv = md[j]; bs = (wv * PPT + j) * 64 + lane; boi = oi[j];
                }
            }
        }
    }
}

// ---------------------------------------------------------------------------
// Gather + 2-layer pointwise MLP + xyz/feat concat, one kernel per level.
// ---------------------------------------------------------------------------
template <int CIN, int F, bool REPEAT>
__global__ __launch_bounds__(256) void mlp_kernel(
    const float* __restrict__ pts, int stride, int n_in,
    const int* __restrict__ idx,
    const float* __restrict__ w1, const float* __restrict__ b1,
    const float* __restrict__ w2, const float* __restrict__ b2,
    float* __restrict__ out, int np)
{
    constexpr int P    = 256 / F;
    constexpr int CINS = REPEAT ? (CIN / 2) : CIN;
    constexpr int LOGF = (F == 16) ? 4 : (F == 32) ? 5 : (F == 64) ? 6 : 7;

    __shared__ float xs[P][CINS];
    __shared__ float h[P][F];

    const int tid = threadIdx.x;
    const int pl  = tid >> LOGF;
    const int c   = tid & (F - 1);
    const int b   = blockIdx.y;
    const int pid = blockIdx.x * P + pl;

    int id = idx[(size_t)b * np + pid];
    id = min(max(id, 0), n_in - 1);       // replay-poison safety
    const float* row = pts + ((size_t)b * n_in + id) * stride;

    if (c < CINS) xs[pl][c] = row[c];
    __syncthreads();

    float acc = b1[c];
#pragma unroll
    for (int k = 0; k < CIN; ++k) {
        const int xk = REPEAT ? (k % 3) : k;
        acc = fmaf(xs[pl][xk], w1[k * F + c], acc);
    }
    h[pl][c] = fmaxf(acc, 0.0f);
    __syncthreads();

    float acc2 = b2[c];
#pragma unroll
    for (int f = 0; f < F; ++f)
        acc2 = fmaf(h[pl][f], w2[f * F + c], acc2);

    float res = (c < 3) ? xs[pl][c] : acc2;
    out[((size_t)b * np + pid) * (size_t)F + c] = res;
}

// ---------------------------------------------------------------------------
// Launch
// ---------------------------------------------------------------------------
extern "C" void kernel_launch(void* const* d_in, const int* in_sizes, int n_in_cnt,
                              void* d_out, int out_size, void* d_ws, size_t ws_size,
                              hipStream_t stream) {
    const float* scene = (const float*)d_in[0];
    const float* w1_1 = (const float*)d_in[1];
    const float* b1_1 = (const float*)d_in[2];
    const float* w2_1 = (const float*)d_in[3];
    const float* b2_1 = (const float*)d_in[4];
    const float* w1_2 = (const float*)d_in[5];
    const float* b1_2 = (const float*)d_in[6];
    const float* w2_2 = (const float*)d_in[7];
    const float* b2_2 = (const float*)d_in[8];
    const float* w1_3 = (const float*)d_in[9];
    const float* b1_3 = (const float*)d_in[10];
    const float* w2_3 = (const float*)d_in[11];
    const float* b2_3 = (const float*)d_in[12];
    const float* w1_4 = (const float*)d_in[13];
    const float* b1_4 = (const float*)d_in[14];
    const float* w2_4 = (const float*)d_in[15];
    const float* b2_4 = (const float*)d_in[16];

    float* out  = (float*)d_out;
    float* out1 = out;                 // [8][4096][16]
    float* out2 = out + 524288;        // [8][2048][32]
    float* out3 = out + 1048576;       // [8][1024][64]
    float* out4 = out + 1572864;       // [8][512][128]

    const int B = 8;

    // workspace layout (ints/floats are both 4B)
    int* p = (int*)d_ws;
    int* idx1 = p;            p += B * 4096;
    int* idx2 = p;            p += B * 2048;
    int* idx3 = p;            p += B * 1024;
    int* idx4 = p;            p += B * 512;
    int* pos01 = p;           p += B;
    int* pos02 = p;           p += B;
    int* pos03 = p;           p += B;
    int* pos04 = p;           p += B;
    float* pxyz1 = (float*)p; p += B * 8192 * 3;
    int*   poi1  = p;         p += B * 8192;
    float* pxyz2 = (float*)p; p += B * 4096 * 3;
    int*   poi2  = p;         p += B * 4096;
    float* pxyz3 = (float*)p; p += B * 2048 * 3;
    int*   poi3  = p;         p += B * 2048;
    float* pxyz4 = (float*)p; p += B * 1024 * 3;
    int*   poi4  = p;

    // Level 1: N=8192 -> 4096, cin=6 (repeat), F=16
    sort_kernel<8192, 512><<<B, 512, 0, stream>>>(scene, 3, pxyz1, poi1, pos01);
    fps_kernel<16, 512, false><<<B, 512, 0, stream>>>(pxyz1, poi1, pos01, 4096, idx1);
    mlp_kernel<6, 16, true><<<dim3(256, B), 256, 0, stream>>>(
        scene, 3, 8192, idx1, w1_1, b1_1, w2_1, b2_1, out1, 4096);

    // Level 2: 4096 -> 2048, cin=16, F=32 (mirror 48KB)
    sort_kernel<4096, 512><<<B, 512, 0, stream>>>(out1, 16, pxyz2, poi2, pos02);
    fps_kernel<8, 512, true><<<B, 512, 0, stream>>>(pxyz2, poi2, pos02, 2048, idx2);
    mlp_kernel<16, 32, false><<<dim3(256, B), 256, 0, stream>>>(
        out1, 16, 4096, idx2, w1_2, b1_2, w2_2, b2_2, out2, 2048);

    // Level 3: 2048 -> 1024, cin=32, F=64 (256 thr, mirror 24KB)
    sort_kernel<2048, 256><<<B, 256, 0, stream>>>(out2, 32, pxyz3, poi3, pos03);
    fps_kernel<8, 256, true><<<B, 256, 0, stream>>>(pxyz3, poi3, pos03, 1024, idx3);
    mlp_kernel<32, 64, false><<<dim3(256, B), 256, 0, stream>>>(
        out2, 32, 2048, idx3, w1_3, b1_3, w2_3, b2_3, out3, 1024);

    // Level 4: 1024 -> 512, cin=64, F=128 (256 thr, mirror 12KB)
    sort_kernel<1024, 256><<<B, 256, 0, stream>>>(out3, 64, pxyz4, poi4, pos04);
    fps_kernel<4, 256, true><<<B, 256, 0, stream>>>(pxyz4, poi4, pos04, 512, idx4);
    mlp_kernel<64, 128, false><<<dim3(256, B), 256, 0, stream>>>(
        out3, 64, 1024, idx4, w1_4, b1_4, w2_4, b2_4, out4, 512);
}

// Round 8
// 10608.414 us; speedup vs baseline: 1.0201x; 1.0201x over previous
//
#include <hip/hip_runtime.h>
#include <hip/hip_bf16.h>

// ---------------------------------------------------------------------------
// Strict f64 squared distance matching numpy float64:
//   d = ((dx*dx + dy*dy) + dz*dz), every op individually rounded, no FMA.
// ---------------------------------------------------------------------------
__device__ __forceinline__ double dist2d(float x, float y, float z,
                                         double px, double py, double pz) {
    double dx = __dsub_rn((double)x, px);
    double dy = __dsub_rn((double)y, py);
    double dz = __dsub_rn((double)z, pz);
    double a  = __dmul_rn(dx, dx);
    double b  = __dmul_rn(dy, dy);
    double c  = __dmul_rn(dz, dz);
    return __dadd_rn(__dadd_rn(a, b), c);
}

// DPP move; lanes with invalid source keep their own value (bound_ctrl=false).
template <int CTRL>
__device__ __forceinline__ double dpp_f64_keep(double v) {
    long long b = __double_as_longlong(v);
    int lo = (int)(b & 0xFFFFFFFFLL);
    int hi = (int)(((unsigned long long)b) >> 32);
    int lo2 = __builtin_amdgcn_update_dpp(lo, lo, CTRL, 0xF, 0xF, false);
    int hi2 = __builtin_amdgcn_update_dpp(hi, hi, CTRL, 0xF, 0xF, false);
    return __longlong_as_double(((long long)(unsigned)hi2 << 32) | (unsigned)lo2);
}

template <int CTRL>
__device__ __forceinline__ int dpp_i32_keep(int v) {
    return __builtin_amdgcn_update_dpp(v, v, CTRL, 0xF, 0xF, false);
}

// lane 63 holds max/min over all 64 lanes after these.
__device__ __forceinline__ double wave_max_f64(double v) {
    v = fmax(v, dpp_f64_keep<0x111>(v));
    v = fmax(v, dpp_f64_keep<0x112>(v));
    v = fmax(v, dpp_f64_keep<0x114>(v));
    v = fmax(v, dpp_f64_keep<0x118>(v));
    v = fmax(v, dpp_f64_keep<0x142>(v));
    v = fmax(v, dpp_f64_keep<0x143>(v));
    return v;
}
__device__ __forceinline__ int wave_min_i32(int v) {
    v = min(v, dpp_i32_keep<0x111>(v));
    v = min(v, dpp_i32_keep<0x112>(v));
    v = min(v, dpp_i32_keep<0x114>(v));
    v = min(v, dpp_i32_keep<0x118>(v));
    v = min(v, dpp_i32_keep<0x142>(v));
    v = min(v, dpp_i32_keep<0x143>(v));
    return v;
}

__device__ __forceinline__ double readlane_f64(double v, int l) {
    long long b = __double_as_longlong(v);
    int lo = __builtin_amdgcn_readlane((int)(b & 0xFFFFFFFFLL), l);
    int hi = __builtin_amdgcn_readlane((int)(((unsigned long long)b) >> 32), l);
    return __longlong_as_double(((long long)(unsigned)hi << 32) | (unsigned)lo);
}
__device__ __forceinline__ float readlane_f32(float v, int l) {
    return __int_as_float(__builtin_amdgcn_readlane(__float_as_int(v), l));
}

__device__ __forceinline__ unsigned part1by2(unsigned v) {
    v = (v * 0x00010001u) & 0xFF0000FFu;
    v = (v * 0x00000101u) & 0x0F00F00Fu;
    v = (v * 0x00000011u) & 0xC30C30C3u;
    v = (v * 0x00000005u) & 0x49249249u;
    return v;
}

// ---------------------------------------------------------------------------
// Spatial sort: one block per batch. Bitonic sort of N u32 keys
// (morton18 << 13 | pos) in LDS. Emits perm_xyz, perm_oi, pos0.
// Hash quality affects only skip efficiency, never correctness.
// ---------------------------------------------------------------------------
template <int N, int NT>
__global__ __launch_bounds__(NT) void sort_kernel(
    const float* __restrict__ pts, int stride,
    float* __restrict__ perm_xyz,
    int* __restrict__ perm_oi,
    int* __restrict__ pos0s)
{
    __shared__ unsigned arr[N];
    const int batch = blockIdx.x;
    const int tid   = threadIdx.x;
    const float* base = pts + (size_t)batch * N * stride;

    for (int p = tid; p < N; p += NT) {
        const float* r = base + (size_t)p * stride;
        unsigned xi = (unsigned)fminf(fmaxf((r[0] + 4.0f) * 8.0f, 0.0f), 63.0f);
        unsigned yi = (unsigned)fminf(fmaxf((r[1] + 4.0f) * 8.0f, 0.0f), 63.0f);
        unsigned zi = (unsigned)fminf(fmaxf((r[2] + 4.0f) * 8.0f, 0.0f), 63.0f);
        unsigned code = part1by2(xi) | (part1by2(yi) << 1) | (part1by2(zi) << 2);
        arr[p] = (code << 13) | (unsigned)p;
    }
    __syncthreads();

    for (int size = 2; size <= N; size <<= 1) {
        for (int str = size >> 1; str > 0; str >>= 1) {
            for (int t = tid; t < N / 2; t += NT) {
                int i = ((t & ~(str - 1)) << 1) | (t & (str - 1));
                unsigned a = arr[i], b = arr[i | str];
                bool up = ((i & size) == 0);
                if ((a > b) == up) { arr[i] = b; arr[i | str] = a; }
            }
            __syncthreads();
        }
    }

    for (int s = tid; s < N; s += NT) {
        int p = (int)(arr[s] & 0x1FFFu);
        const float* r = base + (size_t)p * stride;
        float* w = perm_xyz + ((size_t)batch * N + s) * 3;
        w[0] = r[0]; w[1] = r[1]; w[2] = r[2];
        perm_oi[(size_t)batch * N + s] = p;
        if (p == 0) pos0s[batch] = s;
    }
}

// ---------------------------------------------------------------------------
// FPS on Morton-sorted points, one block per batch.
// Bucket b = j*NWAVES + wv (64 contiguous sorted points per (wave,slot)):
// a winner's spatial neighborhood spans ADJACENT buckets -> different waves
// update in parallel; per-slot __any f32 screen gates the exact-f64 work.
// Per-lane state: coords f32 (exact), md f64 (strict numpy-f64 chain),
// screen thresholds, argmax cache (bv, boi, bcx/y/z, holder slot bj).
// Rescan is holder-gated: md only decreases, so (bv,...) stays valid unless
// the lane's holder slot fired. Wave winner's (max, min-oi, coords) ride the
// double-buffered LDS partials (ONE barrier/iter); cross-wave stage uses
// 3-step DPP max + bounded DPP-min-oi tie resolution (no data-dependent
// loops). iout gets original indices.
// ---------------------------------------------------------------------------
template <int PPT, int NT>
__global__ __launch_bounds__(NT, (NT == 512) ? 2 : 1) void fps_kernel(
    const float* __restrict__ perm_xyz,  // [B][N_IN][3]
    const int* __restrict__ perm_oi,     // [B][N_IN]
    const int* __restrict__ pos0s,       // [B]
    int npoints,
    int* __restrict__ idx_out)           // [B][npoints] (original indices)
{
    constexpr int NWAVES = NT / 64;
    constexpr int N_IN   = PPT * NT;

    const int batch = blockIdx.x;
    const int tid   = threadIdx.x;
    const int lane  = tid & 63;
    const int wv    = tid >> 6;

    const float* base   = perm_xyz + (size_t)batch * N_IN * 3;
    const int*   oibase = perm_oi + (size_t)batch * N_IN;
    int* iout = idx_out + (size_t)batch * npoints;

    __shared__ double s_m[2][NWAVES];
    __shared__ int    s_o[2][NWAVES];
    __shared__ float  s_x[2][NWAVES], s_y[2][NWAVES], s_z[2][NWAVES];

    float  cx[PPT], cy[PPT], cz[PPT];
    int    oi[PPT];
    double md[PPT];
    float  th[PPT];

#pragma unroll
    for (int j = 0; j < PPT; ++j) {
        int s = (j * NWAVES + wv) * 64 + lane;
        const float* r = base + (size_t)s * 3;
        cx[j] = r[0]; cy[j] = r[1]; cz[j] = r[2];
        oi[j] = oibase[s];
    }

    // first selected point: ORIGINAL index 0, at sorted position pos0
    int pos0 = min(max(pos0s[batch], 0), N_IN - 1);
    const float* q0r = base + (size_t)pos0 * 3;
    float q0x = q0r[0], q0y = q0r[1], q0z = q0r[2];
    if (tid == 0) iout[0] = 0;

    double bv = -1.0;
    int    boi = 0x7FFFFFFF, bj = 0;
    float  bcx = 0.f, bcy = 0.f, bcz = 0.f;
#pragma unroll
    for (int j = 0; j < PPT; ++j) {
        md[j] = dist2d(cx[j], cy[j], cz[j], (double)q0x, (double)q0y, (double)q0z);
        th[j] = __fmul_rn((float)md[j], 1.000004f);
        if (md[j] > bv) {
            bv = md[j]; boi = oi[j]; bj = j;
            bcx = cx[j]; bcy = cy[j]; bcz = cz[j];
        }
    }

    for (int i = 1; i < npoints; ++i) {
        const int par = i & 1;

        // ---- wave stage: DPP f64 max + bounded min-oi tie resolution ----
        double wmax = readlane_f64(wave_max_f64(bv), 63);
        int cand = (bv == wmax) ? boi : 0x7FFFFFFF;
        int moi  = __builtin_amdgcn_readlane(wave_min_i32(cand), 63);
        unsigned long long sel = __ballot(cand == moi);
        int wl = __ffsll(sel) - 1;
        float wxx = readlane_f32(bcx, wl);
        float wyy = readlane_f32(bcy, wl);
        float wzz = readlane_f32(bcz, wl);
        if (lane == 0) {
            s_m[par][wv] = wmax; s_o[par][wv] = moi;
            s_x[par][wv] = wxx;  s_y[par][wv] = wyy; s_z[par][wv] = wzz;
        }
        __syncthreads();

        // ---- cross-wave stage on NWAVES partials (lanes 0..NWAVES-1) ----
        const int sl = lane & (NWAVES - 1);
        double pm = s_m[par][sl];
        int    po = s_o[par][sl];
        float  px = s_x[par][sl], py = s_y[par][sl], pz = s_z[par][sl];
        double v2 = (lane < NWAVES) ? pm : -1.0;
        v2 = fmax(v2, dpp_f64_keep<0x111>(v2));
        v2 = fmax(v2, dpp_f64_keep<0x112>(v2));
        if (NWAVES == 8) v2 = fmax(v2, dpp_f64_keep<0x114>(v2));
        double gmax = readlane_f64(v2, NWAVES - 1);
        int cand2 = (lane < NWAVES && pm == gmax) ? po : 0x7FFFFFFF;
        int c2m = cand2;
        c2m = min(c2m, dpp_i32_keep<0x111>(c2m));
        c2m = min(c2m, dpp_i32_keep<0x112>(c2m));
        if (NWAVES == 8) c2m = min(c2m, dpp_i32_keep<0x114>(c2m));
        int gmoi = __builtin_amdgcn_readlane(c2m, NWAVES - 1);
        unsigned long long sel2 = __ballot(cand2 == gmoi);
        int wl2 = __ffsll(sel2) - 1;
        float qx = readlane_f32(px, wl2);
        float qy = readlane_f32(py, wl2);
        float qz = readlane_f32(pz, wl2);
        if (tid == 0) iout[i] = min(max(gmoi, 0), N_IN - 1);

        const double qx64 = (double)qx, qy64 = (double)qy, qz64 = (double)qz;

        // ---- per-bucket f32 screen -> wave-uniform fire mask ----
        int fmask = 0;
#pragma unroll
        for (int j = 0; j < PPT; ++j) {
            float dx = cx[j] - qx;
            float dy = cy[j] - qy;
            float dz = cz[j] - qz;
            float d32 = fmaf(dx, dx, fmaf(dy, dy, dz * dz));
            fmask |= (__any(d32 < th[j]) ? (1 << j) : 0);
        }

        if (fmask) {
#pragma unroll
            for (int j = 0; j < PPT; ++j) {
                if (fmask & (1 << j)) {
                    double d = dist2d(cx[j], cy[j], cz[j], qx64, qy64, qz64);
                    md[j] = fmin(md[j], d);   // no-op where screen over-fired
                    th[j] = __fmul_rn((float)md[j], 1.000004f);
                }
            }
            // md only decreases: argmax cache stays valid unless the lane's
            // holder slot fired.
            int need = (fmask >> bj) & 1;
            if (__any(need)) {
                if (need) {
                    bv = -1.0;
#pragma unroll
                    for (int j = 0; j < PPT; ++j) {
                        if (md[j] > bv) {
                            bv = md[j]; boi = oi[j]; bj = j;
                            bcx = cx[j]; bcy = cy[j]; bcz = cz[j];
                        }
                    }
                }
            }
        }
    }
}

// ---------------------------------------------------------------------------
// Gather + 2-layer pointwise MLP + xyz/feat concat, one kernel per level.
// ---------------------------------------------------------------------------
template <int CIN, int F, bool REPEAT>
__global__ __launch_bounds__(256) void mlp_kernel(
    const float* __restrict__ pts, int stride, int n_in,
    const int* __restrict__ idx,
    const float* __restrict__ w1, const float* __restrict__ b1,
    const float* __restrict__ w2, const float* __restrict__ b2,
    float* __restrict__ out, int np)
{
    constexpr int P    = 256 / F;
    constexpr int CINS = REPEAT ? (CIN / 2) : CIN;
    constexpr int LOGF = (F == 16) ? 4 : (F == 32) ? 5 : (F == 64) ? 6 : 7;

    __shared__ float xs[P][CINS];
    __shared__ float h[P][F];

    const int tid = threadIdx.x;
    const int pl  = tid >> LOGF;
    const int c   = tid & (F - 1);
    const int b   = blockIdx.y;
    const int pid = blockIdx.x * P + pl;

    int id = idx[(size_t)b * np + pid];
    id = min(max(id, 0), n_in - 1);       // replay-poison safety
    const float* row = pts + ((size_t)b * n_in + id) * stride;

    if (c < CINS) xs[pl][c] = row[c];
    __syncthreads();

    float acc = b1[c];
#pragma unroll
    for (int k = 0; k < CIN; ++k) {
        const int xk = REPEAT ? (k % 3) : k;
        acc = fmaf(xs[pl][xk], w1[k * F + c], acc);
    }
    h[pl][c] = fmaxf(acc, 0.0f);
    __syncthreads();

    float acc2 = b2[c];
#pragma unroll
    for (int f = 0; f < F; ++f)
        acc2 = fmaf(h[pl][f], w2[f * F + c], acc2);

    float res = (c < 3) ? xs[pl][c] : acc2;
    out[((size_t)b * np + pid) * (size_t)F + c] = res;
}

// ---------------------------------------------------------------------------
// Launch
// ---------------------------------------------------------------------------
extern "C" void kernel_launch(void* const* d_in, const int* in_sizes, int n_in_cnt,
                              void* d_out, int out_size, void* d_ws, size_t ws_size,
                              hipStream_t stream) {
    const float* scene = (const float*)d_in[0];
    const float* w1_1 = (const float*)d_in[1];
    const float* b1_1 = (const float*)d_in[2];
    const float* w2_1 = (const float*)d_in[3];
    const float* b2_1 = (const float*)d_in[4];
    const float* w1_2 = (const float*)d_in[5];
    const float* b1_2 = (const float*)d_in[6];
    const float* w2_2 = (const float*)d_in[7];
    const float* b2_2 = (const float*)d_in[8];
    const float* w1_3 = (const float*)d_in[9];
    const float* b1_3 = (const float*)d_in[10];
    const float* w2_3 = (const float*)d_in[11];
    const float* b2_3 = (const float*)d_in[12];
    const float* w1_4 = (const float*)d_in[13];
    const float* b1_4 = (const float*)d_in[14];
    const float* w2_4 = (const float*)d_in[15];
    const float* b2_4 = (const float*)d_in[16];

    float* out  = (float*)d_out;
    float* out1 = out;                 // [8][4096][16]
    float* out2 = out + 524288;        // [8][2048][32]
    float* out3 = out + 1048576;       // [8][1024][64]
    float* out4 = out + 1572864;       // [8][512][128]

    const int B = 8;

    int* p = (int*)d_ws;
    int* idx1 = p;            p += B * 4096;
    int* idx2 = p;            p += B * 2048;
    int* idx3 = p;            p += B * 1024;
    int* idx4 = p;            p += B * 512;
    int* pos01 = p;           p += B;
    int* pos02 = p;           p += B;
    int* pos03 = p;           p += B;
    int* pos04 = p;           p += B;
    float* pxyz1 = (float*)p; p += B * 8192 * 3;
    int*   poi1  = p;         p += B * 8192;
    float* pxyz2 = (float*)p; p += B * 4096 * 3;
    int*   poi2  = p;         p += B * 4096;
    float* pxyz3 = (float*)p; p += B * 2048 * 3;
    int*   poi3  = p;         p += B * 2048;
    float* pxyz4 = (float*)p; p += B * 1024 * 3;
    int*   poi4  = p;

    // Level 1: N=8192 -> 4096, cin=6 (repeat), F=16
    sort_kernel<8192, 512><<<B, 512, 0, stream>>>(scene, 3, pxyz1, poi1, pos01);
    fps_kernel<16, 512><<<B, 512, 0, stream>>>(pxyz1, poi1, pos01, 4096, idx1);
    mlp_kernel<6, 16, true><<<dim3(256, B), 256, 0, stream>>>(
        scene, 3, 8192, idx1, w1_1, b1_1, w2_1, b2_1, out1, 4096);

    // Level 2: 4096 -> 2048, cin=16, F=32
    sort_kernel<4096, 512><<<B, 512, 0, stream>>>(out1, 16, pxyz2, poi2, pos02);
    fps_kernel<8, 512><<<B, 512, 0, stream>>>(pxyz2, poi2, pos02, 2048, idx2);
    mlp_kernel<16, 32, false><<<dim3(256, B), 256, 0, stream>>>(
        out1, 16, 4096, idx2, w1_2, b1_2, w2_2, b2_2, out2, 2048);

    // Level 3: 2048 -> 1024, cin=32, F=64
    sort_kernel<2048, 256><<<B, 256, 0, stream>>>(out2, 32, pxyz3, poi3, pos03);
    fps_kernel<8, 256><<<B, 256, 0, stream>>>(pxyz3, poi3, pos03, 1024, idx3);
    mlp_kernel<32, 64, false><<<dim3(256, B), 256, 0, stream>>>(
        out2, 32, 2048, idx3, w1_3, b1_3, w2_3, b2_3, out3, 1024);

    // Level 4: 1024 -> 512, cin=64, F=128
    sort_kernel<1024, 256><<<B, 256, 0, stream>>>(out3, 64, pxyz4, poi4, pos04);
    fps_kernel<4, 256><<<B, 256, 0, stream>>>(pxyz4, poi4, pos04, 512, idx4);
    mlp_kernel<64, 128, false><<<dim3(256, B), 256, 0, stream>>>(
        out3, 64, 1024, idx4, w1_4, b1_4, w2_4, b2_4, out4, 512);
}